// Round 4
// baseline (433.327 us; speedup 1.0000x reference)
//
#include <hip/hip_runtime.h>
#include <hip/hip_bf16.h>
#include <hip/hip_fp16.h>

// Problem constants
#define B_N 1024
#define D_N 512
#define Q_N 32768
#define QSHIFT (Q_N - B_N)   // queue[j] = j<QSHIFT ? qp[j+B_N] : x[j-QSHIFT]

// Packed fp16 hi/lo layout: phys K = 1024 (cols [0,512)=hi, [512,1024)=lo)
#define KP 1024
#define KL 1536              // logical K: hi.hi + lo.hi + hi.lo
#define BKx 32
#define NKB (KL / BKx)       // 48
#define NCH 256              // N chunks of 128

typedef __attribute__((ext_vector_type(8))) _Float16 half8;
typedef __attribute__((ext_vector_type(4))) float f32x4;

__device__ __forceinline__ void top2_update(float d, int j,
                                            float& d1, int& i1, float& d2, int& i2) {
  if (d < d1 || (d == d1 && j < i1)) { d2 = d1; i2 = i1; d1 = d; i1 = j; }
  else if (d < d2 || (d == d2 && j < i2)) { d2 = d; i2 = j; }
}

// ---------------------------------------------------------------------------
// Prep: build fp16 hi|lo packed rows for queue (Qpk) and x (Apk), plus exact
// fp32 squared norms of queue rows. One wave per row.
// ---------------------------------------------------------------------------
__global__ __launch_bounds__(256) void prep_kernel(const float* __restrict__ x,
                                                   const float* __restrict__ qp,
                                                   _Float16* __restrict__ Qpk,
                                                   _Float16* __restrict__ Apk,
                                                   float* __restrict__ q2n) {
  const int row  = blockIdx.x * 4 + (threadIdx.x >> 6);   // 0..Q_N+B_N-1
  const int lane = threadIdx.x & 63;
  const bool is_q = row < Q_N;
  const float* src;
  _Float16* dst;
  if (is_q) {
    src = (row < QSHIFT) ? qp + (size_t)(row + B_N) * D_N
                         : x  + (size_t)(row - QSHIFT) * D_N;
    dst = Qpk + (size_t)row * KP;
  } else {
    src = x + (size_t)(row - Q_N) * D_N;
    dst = Apk + (size_t)(row - Q_N) * KP;
  }
  const float4* p = (const float4*)src;
  float4 a = p[lane * 2], b = p[lane * 2 + 1];
  float v[8] = {a.x, a.y, a.z, a.w, b.x, b.y, b.z, b.w};
  _Float16 hi[8] __attribute__((aligned(16)));
  _Float16 lo[8] __attribute__((aligned(16)));
  float s = 0.0f;
  #pragma unroll
  for (int u = 0; u < 8; ++u) {
    s += v[u] * v[u];
    hi[u] = (_Float16)v[u];
    lo[u] = (_Float16)(v[u] - (float)hi[u]);
  }
  *(uint4*)(dst + lane * 8)       = *(const uint4*)hi;
  *(uint4*)(dst + 512 + lane * 8) = *(const uint4*)lo;
  if (is_q) {
    #pragma unroll
    for (int off = 32; off; off >>= 1) s += __shfl_down(s, off);
    if (lane == 0) q2n[row] = s;
  }
}

// ---------------------------------------------------------------------------
// Main: 128x128 tile fp16 MFMA GEMM over logical K=1536 (hi/lo compensated).
// 3-buffer LDS ring, 2-deep prefetch, COUNTED vmcnt(4) (never 0 in steady
// state), setprio around MFMA, XOR-swizzled LDS, XCD-bijective grid,
// fused per-row top-2 epilogue.
// ---------------------------------------------------------------------------
__global__ __launch_bounds__(256, 3) void nn_mfma(const _Float16* __restrict__ Apk,
                                                  const _Float16* __restrict__ Qpk,
                                                  const float* __restrict__ q2n,
                                                  float4* __restrict__ partial) {
  __shared__ __align__(128) char smem[49152];   // 3 bufs x (A 8K | B 8K)

  // XCD-bijective swizzle, mblk fastest: XCD k owns chunks [k*32,(k+1)*32),
  // all 8 m-blocks of a chunk run consecutively on one XCD -> B-panel L2-hits.
  const int bid  = blockIdx.x;                 // 0..2047
  const int work = (bid & 7) * 256 + (bid >> 3);
  const int chunk = work >> 3;                 // 0..255
  const int mblk  = work & 7;                  // 0..7
  const int n0 = chunk * 128;
  const int i0 = mblk * 128;

  const int t = threadIdx.x;
  const int lane = t & 63;
  const int wv = t >> 6;               // wave 0..3
  const int wm = (wv >> 1) * 64;       // wave m-offset
  const int wn = (wv & 1) * 64;        // wave n-offset
  const int srow = lane >> 2;          // staging row within 16-row chunk
  // pre-swizzled global colgroup: linear LDS slot (l&3) holds logical
  // group (l&3)^((l>>3)&3)  [slot(r,g) = g ^ ((r>>1)&3), r = l>>2]
  const int gcol = (((lane & 3) ^ ((lane >> 3) & 3)) * 8);
  const int fr = lane & 15;
  const int fg = lane >> 4;
  // read-side swizzled byte offset within a 64B row for colgroup fg
  const int rswz = (fg ^ ((fr >> 1) & 3)) * 16;

  f32x4 acc[4][4] = {};

  auto stage = [&](int buf, int kb) {
    int ka, kq;
    if (kb < 16)      { ka = kb * 32;              kq = ka; }              // hi.hi
    else if (kb < 32) { ka = 512 + (kb - 16) * 32; kq = (kb - 16) * 32; }  // lo.hi
    else              { ka = (kb - 32) * 32;       kq = 512 + (kb - 32) * 32; } // hi.lo
    char* base = smem + buf * 16384;
    #pragma unroll
    for (int c = 0; c < 2; ++c) {
      const int r = c * 64 + wv * 16;   // wave-uniform row base
      const _Float16* ga = Apk + (size_t)(i0 + r + srow) * KP + ka + gcol;
      const _Float16* gb = Qpk + (size_t)(n0 + r + srow) * KP + kq + gcol;
      __builtin_amdgcn_global_load_lds(
          (const __attribute__((address_space(1))) void*)ga,
          (__attribute__((address_space(3))) void*)(base + r * 64), 16, 0, 0);
      __builtin_amdgcn_global_load_lds(
          (const __attribute__((address_space(1))) void*)gb,
          (__attribute__((address_space(3))) void*)(base + 8192 + r * 64), 16, 0, 0);
    }
  };

  // prologue: fill ring 2 deep (4 VMEM per wave per tile)
  stage(0, 0);
  stage(1, 1);
  asm volatile("s_waitcnt vmcnt(4)" ::: "memory");  // tile 0 landed, tile 1 in flight
  __syncthreads();

  int cur = 0;
  for (int kb = 0; kb < NKB; ++kb) {
    // issue prefetch for kb+2 into the buffer freed LAST iteration
    if (kb + 2 < NKB) {
      int nxt = cur + 2; if (nxt >= 3) nxt -= 3;
      stage(nxt, kb + 2);
    }

    const char* base = smem + cur * 16384;
    half8 af[4], bf[4];
    #pragma unroll
    for (int mi = 0; mi < 4; ++mi)
      af[mi] = *(const half8*)(base + (wm + mi * 16 + fr) * 64 + rswz);
    #pragma unroll
    for (int ni = 0; ni < 4; ++ni)
      bf[ni] = *(const half8*)(base + 8192 + (wn + ni * 16 + fr) * 64 + rswz);

    __builtin_amdgcn_s_setprio(1);
    #pragma unroll
    for (int mi = 0; mi < 4; ++mi)
      #pragma unroll
      for (int ni = 0; ni < 4; ++ni)
        acc[mi][ni] = __builtin_amdgcn_mfma_f32_16x16x32_f16(af[mi], bf[ni], acc[mi][ni], 0, 0, 0);
    __builtin_amdgcn_s_setprio(0);

    // counted wait: kb+1's 4 loads (oldest) must be done; kb+2's 4 stay in flight
    if (kb < NKB - 2) {
      asm volatile("s_waitcnt vmcnt(4)" ::: "memory");
    } else {
      asm volatile("s_waitcnt vmcnt(0)" ::: "memory");
    }
    __syncthreads();
    cur = (cur == 2) ? 0 : cur + 1;
  }

  // ---- epilogue: d' = q2[j] - 2*S, block-level top-2 per m-row ----
  float4 (*red)[8] = (float4(*)[8])smem;   // overlay: [128 rows][8 subcols]

  float q2v[4];
  #pragma unroll
  for (int ni = 0; ni < 4; ++ni) q2v[ni] = q2n[n0 + wn + ni * 16 + fr];

  #pragma unroll
  for (int mi = 0; mi < 4; ++mi) {
    #pragma unroll
    for (int r = 0; r < 4; ++r) {
      float d1 = 3.4e38f, d2v = 3.4e38f;
      int   i1 = 0x7fffffff, i2v = 0x7fffffff;
      #pragma unroll
      for (int ni = 0; ni < 4; ++ni) {
        const float d = q2v[ni] - 2.0f * acc[mi][ni][r];
        top2_update(d, n0 + wn + ni * 16 + fr, d1, i1, d2v, i2v);
      }
      #pragma unroll
      for (int off = 1; off <= 2; off <<= 1) {
        float e1 = __shfl_xor(d1, off);  int j1 = __shfl_xor(i1, off);
        float e2 = __shfl_xor(d2v, off); int j2 = __shfl_xor(i2v, off);
        top2_update(e1, j1, d1, i1, d2v, i2v);
        top2_update(e2, j2, d1, i1, d2v, i2v);
      }
      if ((lane & 3) == 0)
        red[wm + mi * 16 + fg * 4 + r][(wv & 1) * 4 + (fr >> 2)] =
            make_float4(d1, __int_as_float(i1), d2v, __int_as_float(i2v));
    }
  }
  __syncthreads();

  {
    const int row = t >> 1, part = t & 1;
    float d1 = 3.4e38f, d2 = 3.4e38f;
    int   i1 = 0x7fffffff, i2 = 0x7fffffff;
    #pragma unroll
    for (int u = 0; u < 4; ++u) {
      float4 v = red[row][part * 4 + u];
      top2_update(v.x, __float_as_int(v.y), d1, i1, d2, i2);
      top2_update(v.z, __float_as_int(v.w), d1, i1, d2, i2);
    }
    float e1 = __shfl_xor(d1, 1); int j1 = __shfl_xor(i1, 1);
    float e2 = __shfl_xor(d2, 1); int j2 = __shfl_xor(i2, 1);
    top2_update(e1, j1, d1, i1, d2, i2);
    top2_update(e2, j2, d1, i1, d2, i2);
    if (part == 0)
      partial[(size_t)(i0 + row) * NCH + chunk] =
          make_float4(d1, __int_as_float(i1), d2, __int_as_float(i2));
  }
}

// ---------------------------------------------------------------------------
// Merge 256 partial top-2s per row, pick 2nd-smallest, gather queue row.
// ---------------------------------------------------------------------------
__global__ __launch_bounds__(128) void nn_merge256(const float* __restrict__ x,
                                                   const float* __restrict__ qp,
                                                   const float4* __restrict__ partial,
                                                   float* __restrict__ out) {
  const int row = blockIdx.x;
  const int t   = threadIdx.x;
  __shared__ int s_nn;
  if (t < 64) {
    float d1 = 3.4e38f, d2 = 3.4e38f;
    int   i1 = 0x7fffffff, i2 = 0x7fffffff;
    #pragma unroll
    for (int u = 0; u < 4; ++u) {
      float4 v = partial[(size_t)row * NCH + u * 64 + t];
      top2_update(v.x, __float_as_int(v.y), d1, i1, d2, i2);
      top2_update(v.z, __float_as_int(v.w), d1, i1, d2, i2);
    }
    #pragma unroll
    for (int off = 1; off < 64; off <<= 1) {
      float e1 = __shfl_xor(d1, off); int j1 = __shfl_xor(i1, off);
      float e2 = __shfl_xor(d2, off); int j2 = __shfl_xor(i2, off);
      top2_update(e1, j1, d1, i1, d2, i2);
      top2_update(e2, j2, d1, i1, d2, i2);
    }
    if (t == 0) s_nn = i2;
  }
  __syncthreads();
  const int nn = s_nn;
  const float* src = (nn < QSHIFT) ? qp + (size_t)(nn + B_N) * D_N
                                   : x  + (size_t)(nn - QSHIFT) * D_N;
  ((float4*)(out + (size_t)row * D_N))[t] = ((const float4*)src)[t];
}

// ===========================================================================
// Fallback fp32 path — used only if ws_size is too small for the fp16 pack.
// ===========================================================================
#define TM 64
#define TN 64
#define BKf 16
#define JCHUNK 512
#define NCHUNK (Q_N / JCHUNK)

__global__ __launch_bounds__(256) void qnorm_kernel(const float* __restrict__ x,
                                                    const float* __restrict__ qp,
                                                    float* __restrict__ q2) {
  const int row  = blockIdx.x * 4 + (threadIdx.x >> 6);
  const int lane = threadIdx.x & 63;
  const float* src = (row < QSHIFT) ? (qp + (size_t)(row + B_N) * D_N)
                                    : (x  + (size_t)(row - QSHIFT) * D_N);
  const float4* p = (const float4*)src;
  float4 a = p[lane];
  float4 b = p[lane + 64];
  float s = a.x*a.x + a.y*a.y + a.z*a.z + a.w*a.w
          + b.x*b.x + b.y*b.y + b.z*b.z + b.w*b.w;
  #pragma unroll
  for (int off = 32; off; off >>= 1) s += __shfl_down(s, off);
  if (lane == 0) q2[row] = s;
}

__global__ __launch_bounds__(256) void nn_main(const float* __restrict__ x,
                                               const float* __restrict__ qp,
                                               const float* __restrict__ q2,
                                               float4* __restrict__ partial) {
  __shared__ float As[BKf][TM];
  __shared__ float Bs[BKf][TN];
  __shared__ float4 red[TM][16];
  const int chunk = blockIdx.x;
  const int i0    = blockIdx.y * TM;
  const int t     = threadIdx.x;
  const int tx    = t & 15;
  const int ty    = t >> 4;
  const int lrow  = t >> 2;
  const int kp    = t & 3;
  float d1[4], d2v[4];
  int   i1[4], i2v[4];
  #pragma unroll
  for (int m = 0; m < 4; ++m) { d1[m] = 3.4e38f; d2v[m] = 3.4e38f; i1[m] = 0x7fffffff; i2v[m] = 0x7fffffff; }
  const int j_base = chunk * JCHUNK;
  for (int jt = 0; jt < JCHUNK / TN; ++jt) {
    const int j0 = j_base + jt * TN;
    float acc[4][4] = {};
    const int jr = j0 + lrow;
    const float* bsrc = (jr < QSHIFT) ? (qp + (size_t)(jr + B_N) * D_N)
                                      : (x  + (size_t)(jr - QSHIFT) * D_N);
    const float* asrc = x + (size_t)(i0 + lrow) * D_N;
    for (int k0 = 0; k0 < D_N; k0 += BKf) {
      float4 a4 = *(const float4*)&asrc[k0 + kp * 4];
      float4 b4 = *(const float4*)&bsrc[k0 + kp * 4];
      __syncthreads();
      As[kp*4+0][lrow] = a4.x; As[kp*4+1][lrow] = a4.y;
      As[kp*4+2][lrow] = a4.z; As[kp*4+3][lrow] = a4.w;
      Bs[kp*4+0][lrow] = b4.x; Bs[kp*4+1][lrow] = b4.y;
      Bs[kp*4+2][lrow] = b4.z; Bs[kp*4+3][lrow] = b4.w;
      __syncthreads();
      #pragma unroll
      for (int kk = 0; kk < BKf; ++kk) {
        float4 av = *(const float4*)&As[kk][ty * 4];
        float4 bv = *(const float4*)&Bs[kk][tx * 4];
        float am[4] = {av.x, av.y, av.z, av.w};
        float bm[4] = {bv.x, bv.y, bv.z, bv.w};
        #pragma unroll
        for (int m = 0; m < 4; ++m)
          #pragma unroll
          for (int c = 0; c < 4; ++c)
            acc[m][c] = fmaf(am[m], bm[c], acc[m][c]);
      }
    }
    #pragma unroll
    for (int m = 0; m < 4; ++m)
      #pragma unroll
      for (int c = 0; c < 4; ++c) {
        const int j = j0 + tx * 4 + c;
        const float d = q2[j] - 2.0f * acc[m][c];
        top2_update(d, j, d1[m], i1[m], d2v[m], i2v[m]);
      }
  }
  __syncthreads();
  #pragma unroll
  for (int m = 0; m < 4; ++m)
    red[ty * 4 + m][tx] = make_float4(d1[m], __int_as_float(i1[m]),
                                      d2v[m], __int_as_float(i2v[m]));
  __syncthreads();
  if (t < TM) {
    float bd1 = 3.4e38f, bd2 = 3.4e38f;
    int   bi1 = 0x7fffffff, bi2 = 0x7fffffff;
    #pragma unroll
    for (int u = 0; u < 16; ++u) {
      float4 v = red[t][u];
      top2_update(v.x, __float_as_int(v.y), bd1, bi1, bd2, bi2);
      top2_update(v.z, __float_as_int(v.w), bd1, bi1, bd2, bi2);
    }
    partial[(size_t)(i0 + t) * NCHUNK + chunk] =
        make_float4(bd1, __int_as_float(bi1), bd2, __int_as_float(bi2));
  }
}

__global__ __launch_bounds__(128) void nn_merge(const float* __restrict__ x,
                                                const float* __restrict__ qp,
                                                const float4* __restrict__ partial,
                                                float* __restrict__ out) {
  const int row = blockIdx.x;
  const int t   = threadIdx.x;
  __shared__ int s_nn;
  if (t < 64) {
    float4 v = partial[(size_t)row * NCHUNK + t];
    float d1 = v.x, d2 = v.z;
    int   i1 = __float_as_int(v.y), i2 = __float_as_int(v.w);
    #pragma unroll
    for (int off = 1; off < 64; off <<= 1) {
      float e1 = __shfl_xor(d1, off); int j1 = __shfl_xor(i1, off);
      float e2 = __shfl_xor(d2, off); int j2 = __shfl_xor(i2, off);
      top2_update(e1, j1, d1, i1, d2, i2);
      top2_update(e2, j2, d1, i1, d2, i2);
    }
    if (t == 0) s_nn = i2;
  }
  __syncthreads();
  const int nn = s_nn;
  const float* src = (nn < QSHIFT) ? (qp + (size_t)(nn + B_N) * D_N)
                                   : (x  + (size_t)(nn - QSHIFT) * D_N);
  *(float4*)&out[(size_t)row * D_N + t * 4] = *(const float4*)&src[t * 4];
}

// ---------------------------------------------------------------------------
extern "C" void kernel_launch(void* const* d_in, const int* in_sizes, int n_in,
                              void* d_out, int out_size, void* d_ws, size_t ws_size,
                              hipStream_t stream) {
  const float* x  = (const float*)d_in[0];
  const float* qp = (const float*)d_in[1];
  float* out = (float*)d_out;

  const size_t off_apk = 0;
  const size_t off_qpk = off_apk + (size_t)B_N * KP * sizeof(_Float16);     // 2 MB
  const size_t off_q2n = off_qpk + (size_t)Q_N * KP * sizeof(_Float16);     // +64 MB
  const size_t off_par = off_q2n + (size_t)Q_N * sizeof(float);             // +128 KB
  const size_t need    = off_par + (size_t)B_N * NCH * sizeof(float4);      // +4 MB

  if (ws_size >= need) {
    _Float16* Apk = (_Float16*)((char*)d_ws + off_apk);
    _Float16* Qpk = (_Float16*)((char*)d_ws + off_qpk);
    float*    q2n = (float*)((char*)d_ws + off_q2n);
    float4*   par = (float4*)((char*)d_ws + off_par);
    prep_kernel<<<(Q_N + B_N) / 4, 256, 0, stream>>>(x, qp, Qpk, Apk, q2n);
    nn_mfma<<<2048, 256, 0, stream>>>(Apk, Qpk, q2n, par);
    nn_merge256<<<B_N, 128, 0, stream>>>(x, qp, par, out);
  } else {
    float*  q2      = (float*)d_ws;
    float4* partial = (float4*)((char*)d_ws + Q_N * sizeof(float));
    qnorm_kernel<<<Q_N / 4, 256, 0, stream>>>(x, qp, q2);
    nn_main<<<dim3(NCHUNK, B_N / TM), 256, 0, stream>>>(x, qp, q2, partial);
    nn_merge<<<B_N, 128, 0, stream>>>(x, qp, partial, out);
  }
}

// Round 5
// 416.021 us; speedup vs baseline: 1.0416x; 1.0416x over previous
//
#include <hip/hip_runtime.h>
#include <hip/hip_bf16.h>
#include <hip/hip_fp16.h>

// Problem constants
#define B_N 1024
#define D_N 512
#define Q_N 32768
#define QSHIFT (Q_N - B_N)   // queue[j] = j<QSHIFT ? qp[j+B_N] : x[j-QSHIFT]

// Packed fp16 hi/lo layout: phys K = 1024 (cols [0,512)=hi, [512,1024)=lo)
#define KP 1024
#define KL 1536              // logical K: hi.hi + lo.hi + hi.lo
#define BKx 32
#define NKB (KL / BKx)       // 48
#define NCH 256              // N chunks of 128

typedef __attribute__((ext_vector_type(8))) _Float16 half8;
typedef __attribute__((ext_vector_type(4))) float f32x4;

__device__ __forceinline__ void top2_update(float d, int j,
                                            float& d1, int& i1, float& d2, int& i2) {
  if (d < d1 || (d == d1 && j < i1)) { d2 = d1; i2 = i1; d1 = d; i1 = j; }
  else if (d < d2 || (d == d2 && j < i2)) { d2 = d; i2 = j; }
}

// ---------------------------------------------------------------------------
// Prep: build fp16 hi|lo packed rows for queue (Qpk) and x (Apk), plus exact
// fp32 squared norms of queue rows. One wave per row.
// ---------------------------------------------------------------------------
__global__ __launch_bounds__(256) void prep_kernel(const float* __restrict__ x,
                                                   const float* __restrict__ qp,
                                                   _Float16* __restrict__ Qpk,
                                                   _Float16* __restrict__ Apk,
                                                   float* __restrict__ q2n) {
  const int row  = blockIdx.x * 4 + (threadIdx.x >> 6);   // 0..Q_N+B_N-1
  const int lane = threadIdx.x & 63;
  const bool is_q = row < Q_N;
  const float* src;
  _Float16* dst;
  if (is_q) {
    src = (row < QSHIFT) ? qp + (size_t)(row + B_N) * D_N
                         : x  + (size_t)(row - QSHIFT) * D_N;
    dst = Qpk + (size_t)row * KP;
  } else {
    src = x + (size_t)(row - Q_N) * D_N;
    dst = Apk + (size_t)(row - Q_N) * KP;
  }
  const float4* p = (const float4*)src;
  float4 a = p[lane * 2], b = p[lane * 2 + 1];
  float v[8] = {a.x, a.y, a.z, a.w, b.x, b.y, b.z, b.w};
  _Float16 hi[8] __attribute__((aligned(16)));
  _Float16 lo[8] __attribute__((aligned(16)));
  float s = 0.0f;
  #pragma unroll
  for (int u = 0; u < 8; ++u) {
    s += v[u] * v[u];
    hi[u] = (_Float16)v[u];
    lo[u] = (_Float16)(v[u] - (float)hi[u]);
  }
  *(uint4*)(dst + lane * 8)       = *(const uint4*)hi;
  *(uint4*)(dst + 512 + lane * 8) = *(const uint4*)lo;
  if (is_q) {
    #pragma unroll
    for (int off = 32; off; off >>= 1) s += __shfl_down(s, off);
    if (lane == 0) q2n[row] = s;
  }
}

// ---------------------------------------------------------------------------
// Main: 128x128 tile fp16 MFMA GEMM over logical K=1536 (hi/lo compensated).
// 3-buffer LDS ring, 2-deep prefetch, RAW s_barrier (no implicit vmcnt(0)
// drain — the round-4 lesson) + counted vmcnt(4), setprio around MFMA,
// XOR-swizzled LDS, XCD-bijective grid, fused per-row top-2 epilogue.
// ---------------------------------------------------------------------------
__global__ __launch_bounds__(256, 3) void nn_mfma(const _Float16* __restrict__ Apk,
                                                  const _Float16* __restrict__ Qpk,
                                                  const float* __restrict__ q2n,
                                                  float4* __restrict__ partial) {
  __shared__ __align__(128) char smem[49152];   // 3 bufs x (A 8K | B 8K)

  // XCD-bijective swizzle, mblk fastest: XCD k owns chunks [k*32,(k+1)*32),
  // all 8 m-blocks of a chunk run consecutively on one XCD -> B-panel L2-hits.
  const int bid  = blockIdx.x;                 // 0..2047
  const int work = (bid & 7) * 256 + (bid >> 3);
  const int chunk = work >> 3;                 // 0..255
  const int mblk  = work & 7;                  // 0..7
  const int n0 = chunk * 128;
  const int i0 = mblk * 128;

  const int t = threadIdx.x;
  const int lane = t & 63;
  const int wv = t >> 6;               // wave 0..3
  const int wm = (wv >> 1) * 64;       // wave m-offset
  const int wn = (wv & 1) * 64;        // wave n-offset
  const int srow = lane >> 2;          // staging row within 16-row chunk
  // pre-swizzled global colgroup: linear LDS slot (l&3) holds logical
  // group (l&3)^((l>>3)&3)  [slot(r,g) = g ^ ((r>>1)&3), r = l>>2]
  const int gcol = (((lane & 3) ^ ((lane >> 3) & 3)) * 8);
  const int fr = lane & 15;
  const int fg = lane >> 4;
  // read-side swizzled byte offset within a 64B row for colgroup fg
  const int rswz = (fg ^ ((fr >> 1) & 3)) * 16;

  f32x4 acc[4][4] = {};

  auto stage = [&](int buf, int kb) {
    int ka, kq;
    if (kb < 16)      { ka = kb * 32;              kq = ka; }              // hi.hi
    else if (kb < 32) { ka = 512 + (kb - 16) * 32; kq = (kb - 16) * 32; }  // lo.hi
    else              { ka = (kb - 32) * 32;       kq = 512 + (kb - 32) * 32; } // hi.lo
    char* base = smem + buf * 16384;
    #pragma unroll
    for (int c = 0; c < 2; ++c) {
      const int r = c * 64 + wv * 16;   // wave-uniform row base
      const _Float16* ga = Apk + (size_t)(i0 + r + srow) * KP + ka + gcol;
      const _Float16* gb = Qpk + (size_t)(n0 + r + srow) * KP + kq + gcol;
      __builtin_amdgcn_global_load_lds(
          (const __attribute__((address_space(1))) void*)ga,
          (__attribute__((address_space(3))) void*)(base + r * 64), 16, 0, 0);
      __builtin_amdgcn_global_load_lds(
          (const __attribute__((address_space(1))) void*)gb,
          (__attribute__((address_space(3))) void*)(base + 8192 + r * 64), 16, 0, 0);
    }
  };

  // prologue: fill ring 2 deep (4 VMEM per wave per tile)
  stage(0, 0);
  stage(1, 1);
  asm volatile("s_waitcnt vmcnt(4)" ::: "memory");  // tile 0 landed, tile 1 in flight
  __builtin_amdgcn_s_barrier();

  int cur = 0;
  for (int kb = 0; kb < NKB; ++kb) {
    // issue prefetch for kb+2 into the buffer consumed last iteration
    if (kb + 2 < NKB) {
      int nxt = cur + 2; if (nxt >= 3) nxt -= 3;
      stage(nxt, kb + 2);
    }

    const char* base = smem + cur * 16384;
    half8 af[4], bf[4];
    #pragma unroll
    for (int mi = 0; mi < 4; ++mi)
      af[mi] = *(const half8*)(base + (wm + mi * 16 + fr) * 64 + rswz);
    #pragma unroll
    for (int ni = 0; ni < 4; ++ni)
      bf[ni] = *(const half8*)(base + 8192 + (wn + ni * 16 + fr) * 64 + rswz);

    __builtin_amdgcn_s_setprio(1);
    #pragma unroll
    for (int mi = 0; mi < 4; ++mi)
      #pragma unroll
      for (int ni = 0; ni < 4; ++ni)
        acc[mi][ni] = __builtin_amdgcn_mfma_f32_16x16x32_f16(af[mi], bf[ni], acc[mi][ni], 0, 0, 0);
    __builtin_amdgcn_s_setprio(0);

    // counted wait: kb+1's 4 loads (oldest) must be done; kb+2's stay in flight.
    // RAW barrier: does NOT drain vmcnt (unlike __syncthreads).
    if (kb < NKB - 2) {
      asm volatile("s_waitcnt vmcnt(4)" ::: "memory");
    } else {
      asm volatile("s_waitcnt vmcnt(0)" ::: "memory");
    }
    __builtin_amdgcn_s_barrier();
    cur = (cur == 2) ? 0 : cur + 1;
  }

  // ---- epilogue: d' = q2[j] - 2*S, block-level top-2 per m-row ----
  float4 (*red)[8] = (float4(*)[8])smem;   // overlay: [128 rows][8 subcols]

  float q2v[4];
  #pragma unroll
  for (int ni = 0; ni < 4; ++ni) q2v[ni] = q2n[n0 + wn + ni * 16 + fr];

  #pragma unroll
  for (int mi = 0; mi < 4; ++mi) {
    #pragma unroll
    for (int r = 0; r < 4; ++r) {
      float d1 = 3.4e38f, d2v = 3.4e38f;
      int   i1 = 0x7fffffff, i2v = 0x7fffffff;
      #pragma unroll
      for (int ni = 0; ni < 4; ++ni) {
        const float d = q2v[ni] - 2.0f * acc[mi][ni][r];
        top2_update(d, n0 + wn + ni * 16 + fr, d1, i1, d2v, i2v);
      }
      #pragma unroll
      for (int off = 1; off <= 2; off <<= 1) {
        float e1 = __shfl_xor(d1, off);  int j1 = __shfl_xor(i1, off);
        float e2 = __shfl_xor(d2v, off); int j2 = __shfl_xor(i2v, off);
        top2_update(e1, j1, d1, i1, d2v, i2v);
        top2_update(e2, j2, d1, i1, d2v, i2v);
      }
      if ((lane & 3) == 0)
        red[wm + mi * 16 + fg * 4 + r][(wv & 1) * 4 + (fr >> 2)] =
            make_float4(d1, __int_as_float(i1), d2v, __int_as_float(i2v));
    }
  }
  __syncthreads();

  {
    const int row = t >> 1, part = t & 1;
    float d1 = 3.4e38f, d2 = 3.4e38f;
    int   i1 = 0x7fffffff, i2 = 0x7fffffff;
    #pragma unroll
    for (int u = 0; u < 4; ++u) {
      float4 v = red[row][part * 4 + u];
      top2_update(v.x, __float_as_int(v.y), d1, i1, d2, i2);
      top2_update(v.z, __float_as_int(v.w), d1, i1, d2, i2);
    }
    float e1 = __shfl_xor(d1, 1); int j1 = __shfl_xor(i1, 1);
    float e2 = __shfl_xor(d2, 1); int j2 = __shfl_xor(i2, 1);
    top2_update(e1, j1, d1, i1, d2, i2);
    top2_update(e2, j2, d1, i1, d2, i2);
    if (part == 0)
      partial[(size_t)(i0 + row) * NCH + chunk] =
          make_float4(d1, __int_as_float(i1), d2, __int_as_float(i2));
  }
}

// ---------------------------------------------------------------------------
// Merge 256 partial top-2s per row, pick 2nd-smallest, gather queue row.
// ---------------------------------------------------------------------------
__global__ __launch_bounds__(128) void nn_merge256(const float* __restrict__ x,
                                                   const float* __restrict__ qp,
                                                   const float4* __restrict__ partial,
                                                   float* __restrict__ out) {
  const int row = blockIdx.x;
  const int t   = threadIdx.x;
  __shared__ int s_nn;
  if (t < 64) {
    float d1 = 3.4e38f, d2 = 3.4e38f;
    int   i1 = 0x7fffffff, i2 = 0x7fffffff;
    #pragma unroll
    for (int u = 0; u < 4; ++u) {
      float4 v = partial[(size_t)row * NCH + u * 64 + t];
      top2_update(v.x, __float_as_int(v.y), d1, i1, d2, i2);
      top2_update(v.z, __float_as_int(v.w), d1, i1, d2, i2);
    }
    #pragma unroll
    for (int off = 1; off < 64; off <<= 1) {
      float e1 = __shfl_xor(d1, off); int j1 = __shfl_xor(i1, off);
      float e2 = __shfl_xor(d2, off); int j2 = __shfl_xor(i2, off);
      top2_update(e1, j1, d1, i1, d2, i2);
      top2_update(e2, j2, d1, i1, d2, i2);
    }
    if (t == 0) s_nn = i2;
  }
  __syncthreads();
  const int nn = s_nn;
  const float* src = (nn < QSHIFT) ? qp + (size_t)(nn + B_N) * D_N
                                   : x  + (size_t)(nn - QSHIFT) * D_N;
  ((float4*)(out + (size_t)row * D_N))[t] = ((const float4*)src)[t];
}

// ===========================================================================
// Fallback fp32 path — used only if ws_size is too small for the fp16 pack.
// ===========================================================================
#define TM 64
#define TN 64
#define BKf 16
#define JCHUNK 512
#define NCHUNK (Q_N / JCHUNK)

__global__ __launch_bounds__(256) void qnorm_kernel(const float* __restrict__ x,
                                                    const float* __restrict__ qp,
                                                    float* __restrict__ q2) {
  const int row  = blockIdx.x * 4 + (threadIdx.x >> 6);
  const int lane = threadIdx.x & 63;
  const float* src = (row < QSHIFT) ? (qp + (size_t)(row + B_N) * D_N)
                                    : (x  + (size_t)(row - QSHIFT) * D_N);
  const float4* p = (const float4*)src;
  float4 a = p[lane];
  float4 b = p[lane + 64];
  float s = a.x*a.x + a.y*a.y + a.z*a.z + a.w*a.w
          + b.x*b.x + b.y*b.y + b.z*b.z + b.w*b.w;
  #pragma unroll
  for (int off = 32; off; off >>= 1) s += __shfl_down(s, off);
  if (lane == 0) q2[row] = s;
}

__global__ __launch_bounds__(256) void nn_main(const float* __restrict__ x,
                                               const float* __restrict__ qp,
                                               const float* __restrict__ q2,
                                               float4* __restrict__ partial) {
  __shared__ float As[BKf][TM];
  __shared__ float Bs[BKf][TN];
  __shared__ float4 red[TM][16];
  const int chunk = blockIdx.x;
  const int i0    = blockIdx.y * TM;
  const int t     = threadIdx.x;
  const int tx    = t & 15;
  const int ty    = t >> 4;
  const int lrow  = t >> 2;
  const int kp    = t & 3;
  float d1[4], d2v[4];
  int   i1[4], i2v[4];
  #pragma unroll
  for (int m = 0; m < 4; ++m) { d1[m] = 3.4e38f; d2v[m] = 3.4e38f; i1[m] = 0x7fffffff; i2v[m] = 0x7fffffff; }
  const int j_base = chunk * JCHUNK;
  for (int jt = 0; jt < JCHUNK / TN; ++jt) {
    const int j0 = j_base + jt * TN;
    float acc[4][4] = {};
    const int jr = j0 + lrow;
    const float* bsrc = (jr < QSHIFT) ? (qp + (size_t)(jr + B_N) * D_N)
                                      : (x  + (size_t)(jr - QSHIFT) * D_N);
    const float* asrc = x + (size_t)(i0 + lrow) * D_N;
    for (int k0 = 0; k0 < D_N; k0 += BKf) {
      float4 a4 = *(const float4*)&asrc[k0 + kp * 4];
      float4 b4 = *(const float4*)&bsrc[k0 + kp * 4];
      __syncthreads();
      As[kp*4+0][lrow] = a4.x; As[kp*4+1][lrow] = a4.y;
      As[kp*4+2][lrow] = a4.z; As[kp*4+3][lrow] = a4.w;
      Bs[kp*4+0][lrow] = b4.x; Bs[kp*4+1][lrow] = b4.y;
      Bs[kp*4+2][lrow] = b4.z; Bs[kp*4+3][lrow] = b4.w;
      __syncthreads();
      #pragma unroll
      for (int kk = 0; kk < BKf; ++kk) {
        float4 av = *(const float4*)&As[kk][ty * 4];
        float4 bv = *(const float4*)&Bs[kk][tx * 4];
        float am[4] = {av.x, av.y, av.z, av.w};
        float bm[4] = {bv.x, bv.y, bv.z, bv.w};
        #pragma unroll
        for (int m = 0; m < 4; ++m)
          #pragma unroll
          for (int c = 0; c < 4; ++c)
            acc[m][c] = fmaf(am[m], bm[c], acc[m][c]);
      }
    }
    #pragma unroll
    for (int m = 0; m < 4; ++m)
      #pragma unroll
      for (int c = 0; c < 4; ++c) {
        const int j = j0 + tx * 4 + c;
        const float d = q2[j] - 2.0f * acc[m][c];
        top2_update(d, j, d1[m], i1[m], d2v[m], i2v[m]);
      }
  }
  __syncthreads();
  #pragma unroll
  for (int m = 0; m < 4; ++m)
    red[ty * 4 + m][tx] = make_float4(d1[m], __int_as_float(i1[m]),
                                      d2v[m], __int_as_float(i2v[m]));
  __syncthreads();
  if (t < TM) {
    float bd1 = 3.4e38f, bd2 = 3.4e38f;
    int   bi1 = 0x7fffffff, bi2 = 0x7fffffff;
    #pragma unroll
    for (int u = 0; u < 16; ++u) {
      float4 v = red[t][u];
      top2_update(v.x, __float_as_int(v.y), bd1, bi1, bd2, bi2);
      top2_update(v.z, __float_as_int(v.w), bd1, bi1, bd2, bi2);
    }
    partial[(size_t)(i0 + t) * NCHUNK + chunk] =
        make_float4(bd1, __int_as_float(bi1), bd2, __int_as_float(bi2));
  }
}

__global__ __launch_bounds__(128) void nn_merge(const float* __restrict__ x,
                                                const float* __restrict__ qp,
                                                const float4* __restrict__ partial,
                                                float* __restrict__ out) {
  const int row = blockIdx.x;
  const int t   = threadIdx.x;
  __shared__ int s_nn;
  if (t < 64) {
    float4 v = partial[(size_t)row * NCHUNK + t];
    float d1 = v.x, d2 = v.z;
    int   i1 = __float_as_int(v.y), i2 = __float_as_int(v.w);
    #pragma unroll
    for (int off = 1; off < 64; off <<= 1) {
      float e1 = __shfl_xor(d1, off); int j1 = __shfl_xor(i1, off);
      float e2 = __shfl_xor(d2, off); int j2 = __shfl_xor(i2, off);
      top2_update(e1, j1, d1, i1, d2, i2);
      top2_update(e2, j2, d1, i1, d2, i2);
    }
    if (t == 0) s_nn = i2;
  }
  __syncthreads();
  const int nn = s_nn;
  const float* src = (nn < QSHIFT) ? (qp + (size_t)(nn + B_N) * D_N)
                                   : (x  + (size_t)(nn - QSHIFT) * D_N);
  *(float4*)&out[(size_t)row * D_N + t * 4] = *(const float4*)&src[t * 4];
}

// ---------------------------------------------------------------------------
extern "C" void kernel_launch(void* const* d_in, const int* in_sizes, int n_in,
                              void* d_out, int out_size, void* d_ws, size_t ws_size,
                              hipStream_t stream) {
  const float* x  = (const float*)d_in[0];
  const float* qp = (const float*)d_in[1];
  float* out = (float*)d_out;

  const size_t off_apk = 0;
  const size_t off_qpk = off_apk + (size_t)B_N * KP * sizeof(_Float16);     // 2 MB
  const size_t off_q2n = off_qpk + (size_t)Q_N * KP * sizeof(_Float16);     // +64 MB
  const size_t off_par = off_q2n + (size_t)Q_N * sizeof(float);             // +128 KB
  const size_t need    = off_par + (size_t)B_N * NCH * sizeof(float4);      // +4 MB

  if (ws_size >= need) {
    _Float16* Apk = (_Float16*)((char*)d_ws + off_apk);
    _Float16* Qpk = (_Float16*)((char*)d_ws + off_qpk);
    float*    q2n = (float*)((char*)d_ws + off_q2n);
    float4*   par = (float4*)((char*)d_ws + off_par);
    prep_kernel<<<(Q_N + B_N) / 4, 256, 0, stream>>>(x, qp, Qpk, Apk, q2n);
    nn_mfma<<<2048, 256, 0, stream>>>(Apk, Qpk, q2n, par);
    nn_merge256<<<B_N, 128, 0, stream>>>(x, qp, par, out);
  } else {
    float*  q2      = (float*)d_ws;
    float4* partial = (float4*)((char*)d_ws + Q_N * sizeof(float));
    qnorm_kernel<<<Q_N / 4, 256, 0, stream>>>(x, qp, q2);
    nn_main<<<dim3(NCHUNK, B_N / TM), 256, 0, stream>>>(x, qp, q2, partial);
    nn_merge<<<B_N, 128, 0, stream>>>(x, qp, partial, out);
  }
}